// Round 4
// baseline (494.865 us; speedup 1.0000x reference)
//
#include <hip/hip_runtime.h>
#include <math.h>

#define BB 2
#define LL 1024
#define DD 1024
#define DI 2048
#define DS 16
#define DC 4
#define DTR 64
#define XD 96      // DTR + 2*DS
#define NC 64      // scan chunks
#define CLEN 16    // steps per chunk (NC*CLEN == LL)

typedef __bf16 bf16x8 __attribute__((ext_vector_type(8)));
typedef __bf16 bf16x4 __attribute__((ext_vector_type(4)));
typedef float  f32x4  __attribute__((ext_vector_type(4)));
typedef const __attribute__((address_space(1))) void* gas_ptr;
typedef __attribute__((address_space(3))) void*       las_ptr;

__device__ __forceinline__ float silu_f(float v){ return v / (1.f + expf(-v)); }

// ---------------- fp32 -> bf16 convert (n % 1024 == 0) ----------------
__global__ __launch_bounds__(256) void f2bf_k(const float* __restrict__ x,
                                              __bf16* __restrict__ o, int n) {
  int i = (blockIdx.x * 256 + threadIdx.x) * 4;
  float4 v = *(const float4*)(x + i);
  o[i + 0] = (__bf16)v.x; o[i + 1] = (__bf16)v.y;
  o[i + 2] = (__bf16)v.z; o[i + 3] = (__bf16)v.w;
}

// ---------------- rmsnorm: one block per row of D=1024, bf16 out ------
__global__ __launch_bounds__(256) void rmsnorm_bf_k(const float* __restrict__ x,
                                                    const float* __restrict__ w,
                                                    __bf16* __restrict__ o) {
  int row = blockIdx.x;
  const float* xr = x + (size_t)row * DD;
  int i4 = threadIdx.x * 4;
  float4 v = *(const float4*)(xr + i4);
  float ss = v.x * v.x + v.y * v.y + v.z * v.z + v.w * v.w;
  for (int off = 32; off; off >>= 1) ss += __shfl_down(ss, off, 64);
  __shared__ float red[4];
  int lane = threadIdx.x & 63, wv = threadIdx.x >> 6;
  if (!lane) red[wv] = ss;
  __syncthreads();
  if (!threadIdx.x) { float t = red[0] + red[1] + red[2] + red[3]; red[0] = rsqrtf(t / DD + 1e-6f); }
  __syncthreads();
  float rs = red[0];
  float4 wv4 = *(const float4*)(w + i4);
  __bf16* orow = o + (size_t)row * DD;
  orow[i4 + 0] = (__bf16)(wv4.x * v.x * rs);
  orow[i4 + 1] = (__bf16)(wv4.y * v.y * rs);
  orow[i4 + 2] = (__bf16)(wv4.z * v.z * rs);
  orow[i4 + 3] = (__bf16)(wv4.w * v.w * rs);
}

// ---------------- bf16 MFMA GEMM: C[M,N] = ep(A[M,K] @ W[N,K]^T) ------
// BM=128 fixed. 4 waves 2x2. Wave tile = 64 x (NI*16). BK=32.
// A row stride = lda (elements); W row stride = K.
// ACT: 0=none 1=silu 2=softplus. OUT_BF: store bf16 else fp32.
// SPLITK>1 requires ATOMIC; bias/resid applied by split kz==0 only.
template<int BN, int NI, bool OUT_BF, int ACT, bool BIAS, bool RESID, int SPLITK, bool ATOMIC>
__global__ __launch_bounds__(256) void mfma_gemm(const __bf16* __restrict__ A, int lda,
                                                 const __bf16* __restrict__ W,
                                                 const float* __restrict__ bias,
                                                 const float* __restrict__ resid,
                                                 void* __restrict__ Cout,
                                                 int M, int N, int K) {
  __shared__ __align__(16) __bf16 As[128 * 32];
  __shared__ __align__(16) __bf16 Bs[BN * 32];
  const int tid = threadIdx.x;
  const int m0 = blockIdx.y * 128;
  const int n0 = blockIdx.x * BN;
  const int kz = blockIdx.z;
  const int lane = tid & 63;
  const int wave = tid >> 6;
  const int wm = wave >> 1, wn = wave & 1;
  const int row16 = lane & 15, quad = lane >> 4;

  f32x4 acc[4][NI];
  #pragma unroll
  for (int i = 0; i < 4; ++i)
    #pragma unroll
    for (int j = 0; j < NI; ++j) acc[i][j] = (f32x4){0.f, 0.f, 0.f, 0.f};

  const int kspan = K / SPLITK;
  const int kbeg = kz * kspan;
  for (int k0 = kbeg; k0 < kbeg + kspan; k0 += 32) {
    #pragma unroll
    for (int t = 0; t < 2; ++t) {
      int flat = t * 256 + tid;
      int r = flat >> 2, kel = (flat & 3) * 8;
      __builtin_amdgcn_global_load_lds(
          (gas_ptr)(A + (size_t)(m0 + r) * lda + k0 + kel),
          (las_ptr)(As + flat * 8), 16, 0, 0);
    }
    constexpr int BCH = BN * 4;
    #pragma unroll
    for (int t = 0; t < (BCH + 255) / 256; ++t) {
      int flat = t * 256 + tid;
      if (BCH >= 256 || flat < BCH) {
        int r = flat >> 2, kel = (flat & 3) * 8;
        __builtin_amdgcn_global_load_lds(
            (gas_ptr)(W + (size_t)(n0 + r) * K + k0 + kel),
            (las_ptr)(Bs + flat * 8), 16, 0, 0);
      }
    }
    __syncthreads();
    bf16x8 af[4], bfr[NI];
    #pragma unroll
    for (int mi = 0; mi < 4; ++mi)
      af[mi] = *(const bf16x8*)&As[(wm * 64 + mi * 16 + row16) * 32 + quad * 8];
    #pragma unroll
    for (int ni = 0; ni < NI; ++ni)
      bfr[ni] = *(const bf16x8*)&Bs[(wn * NI * 16 + ni * 16 + row16) * 32 + quad * 8];
    #pragma unroll
    for (int mi = 0; mi < 4; ++mi)
      #pragma unroll
      for (int ni = 0; ni < NI; ++ni)
        acc[mi][ni] = __builtin_amdgcn_mfma_f32_16x16x32_bf16(af[mi], bfr[ni], acc[mi][ni], 0, 0, 0);
    __syncthreads();
  }

  // epilogue: D[row=quad*4+r][col=lane&15] per 16x16 frag
  #pragma unroll
  for (int mi = 0; mi < 4; ++mi) {
    #pragma unroll
    for (int ni = 0; ni < NI; ++ni) {
      #pragma unroll
      for (int r = 0; r < 4; ++r) {
        int gm = m0 + wm * 64 + mi * 16 + quad * 4 + r;
        int gn = n0 + wn * NI * 16 + ni * 16 + row16;
        float v = acc[mi][ni][r];
        if (ATOMIC) {
          if (kz == 0) {
            if (BIAS)  v += bias[gn];
            if (RESID) v += resid[(size_t)gm * N + gn];
          }
          atomicAdd(&((float*)Cout)[(size_t)gm * N + gn], v);
        } else {
          if (BIAS) v += bias[gn];
          if (ACT == 1) v = silu_f(v);
          else if (ACT == 2) v = (v > 20.f) ? v : log1pf(expf(v));
          if (RESID) v += resid[(size_t)gm * N + gn];
          if (OUT_BF) ((__bf16*)Cout)[(size_t)gm * N + gn] = (__bf16)v;
          else        ((float*)Cout)[(size_t)gm * N + gn] = v;
        }
      }
    }
  }
}

// ---------------- causal depthwise conv (DC=4) + silu, bf16 in/out ----
// 4 consecutive d-columns per thread
__global__ __launch_bounds__(256) void conv_silu_k(const __bf16* __restrict__ xz,
                                                   const float* __restrict__ cw,
                                                   const float* __restrict__ cb,
                                                   __bf16* __restrict__ xc) {
  size_t idx = (size_t)blockIdx.x * 256 + threadIdx.x;   // over BB*LL*(DI/4)
  int d4 = (int)(idx % (DI / 4)) * 4;
  size_t bl = idx / (DI / 4);
  int l = (int)(bl % LL);
  size_t rowbase = (bl - l) * (size_t)(2 * DI);
  float4 cbv = *(const float4*)(cb + d4);
  float a0 = cbv.x, a1 = cbv.y, a2 = cbv.z, a3 = cbv.w;
  #pragma unroll
  for (int k = 0; k < DC; ++k) {
    int ls = l + k - (DC - 1);
    if (ls >= 0) {
      bf16x4 xv = *(const bf16x4*)(xz + rowbase + (size_t)ls * (2 * DI) + d4);
      a0 += cw[(d4 + 0) * DC + k] * (float)xv[0];
      a1 += cw[(d4 + 1) * DC + k] * (float)xv[1];
      a2 += cw[(d4 + 2) * DC + k] * (float)xv[2];
      a3 += cw[(d4 + 3) * DC + k] * (float)xv[3];
    }
  }
  __bf16* o = xc + bl * DI + d4;
  o[0] = (__bf16)silu_f(a0); o[1] = (__bf16)silu_f(a1);
  o[2] = (__bf16)silu_f(a2); o[3] = (__bf16)silu_f(a3);
}

// ---------------- selective scan, 3-pass chunked ----------------
__global__ __launch_bounds__(256) void scan1_k(const float* __restrict__ dt,
                                               const __bf16* __restrict__ xc,
                                               const float* __restrict__ xdbl,
                                               const float* __restrict__ A_log,
                                               float* __restrict__ hch,
                                               float* __restrict__ sdt) {
  const int DBLK = DI / 256;
  int dblk = blockIdx.x % DBLK;
  int c = (blockIdx.x / DBLK) % NC;
  int b = blockIdx.x / (DBLK * NC);
  int d = dblk * 256 + threadIdx.x;
  __shared__ float Bs[CLEN][DS];
  if (threadIdx.x < CLEN * DS) {
    int ll = threadIdx.x / DS, s = threadIdx.x % DS;
    Bs[ll][s] = xdbl[((size_t)b * LL + c * CLEN + ll) * XD + DTR + s];
  }
  __syncthreads();
  float As[DS];
  #pragma unroll
  for (int s = 0; s < DS; ++s) As[s] = -expf(A_log[(size_t)d * DS + s]);
  float h[DS] = {};
  float sum_dt = 0.f;
  for (int t = 0; t < CLEN; ++t) {
    size_t bl = (size_t)b * LL + c * CLEN + t;
    float dtv = dt[bl * DI + d];
    float xv = (float)xc[bl * DI + d];
    float cc = dtv * xv;
    sum_dt += dtv;
    #pragma unroll
    for (int s = 0; s < DS; ++s) h[s] = expf(dtv * As[s]) * h[s] + cc * Bs[t][s];
  }
  size_t base = (((size_t)b * NC + c) * DS) * DI + d;
  #pragma unroll
  for (int s = 0; s < DS; ++s) hch[base + (size_t)s * DI] = h[s];
  sdt[((size_t)b * NC + c) * DI + d] = sum_dt;
}

__global__ __launch_bounds__(256) void scan2_k(float* __restrict__ hch,
                                               const float* __restrict__ sdt,
                                               const float* __restrict__ A_log) {
  const int DBLK = DI / 256;
  int dblk = blockIdx.x % DBLK;
  int s = (blockIdx.x / DBLK) % DS;
  int b = blockIdx.x / (DBLK * DS);
  int d = dblk * 256 + threadIdx.x;
  float As = -expf(A_log[(size_t)d * DS + s]);
  float hs = 0.f;
  for (int c = 0; c < NC; ++c) {
    size_t idx = (((size_t)b * NC + c) * DS + s) * DI + d;
    float local_final = hch[idx];
    hch[idx] = hs;
    float sum_dt = sdt[((size_t)b * NC + c) * DI + d];
    hs = expf(sum_dt * As) * hs + local_final;
  }
}

__global__ __launch_bounds__(256) void scan3_k(const float* __restrict__ dt,
                                               const __bf16* __restrict__ xc,
                                               const __bf16* __restrict__ xz,
                                               const float* __restrict__ xdbl,
                                               const float* __restrict__ hch,
                                               const float* __restrict__ A_log,
                                               const float* __restrict__ Dp,
                                               __bf16* __restrict__ yb) {
  const int DBLK = DI / 256;
  int dblk = blockIdx.x % DBLK;
  int c = (blockIdx.x / DBLK) % NC;
  int b = blockIdx.x / (DBLK * NC);
  int d = dblk * 256 + threadIdx.x;
  __shared__ float Bs[CLEN][DS], Cs[CLEN][DS];
  if (threadIdx.x < CLEN * DS) {
    int ll = threadIdx.x / DS, s = threadIdx.x % DS;
    size_t bl = (size_t)b * LL + c * CLEN + ll;
    Bs[ll][s] = xdbl[bl * XD + DTR + s];
    Cs[ll][s] = xdbl[bl * XD + DTR + DS + s];
  }
  __syncthreads();
  float As[DS], h[DS];
  #pragma unroll
  for (int s = 0; s < DS; ++s) As[s] = -expf(A_log[(size_t)d * DS + s]);
  size_t base = (((size_t)b * NC + c) * DS) * DI + d;
  #pragma unroll
  for (int s = 0; s < DS; ++s) h[s] = hch[base + (size_t)s * DI];
  float Dv = Dp[d];
  for (int t = 0; t < CLEN; ++t) {
    size_t bl = (size_t)b * LL + c * CLEN + t;
    float dtv = dt[bl * DI + d];
    float xv = (float)xc[bl * DI + d];
    float cc = dtv * xv;
    float y = 0.f;
    #pragma unroll
    for (int s = 0; s < DS; ++s) {
      h[s] = expf(dtv * As[s]) * h[s] + cc * Bs[t][s];
      y += h[s] * Cs[t][s];
    }
    float zv = (float)xz[bl * (size_t)(2 * DI) + DI + d];
    yb[bl * DI + d] = (__bf16)((y + Dv * xv) * silu_f(zv));
  }
}

// ---------------- launch ----------------
extern "C" void kernel_launch(void* const* d_in, const int* in_sizes, int n_in,
                              void* d_out, int out_size, void* d_ws, size_t ws_size,
                              hipStream_t stream) {
  const float* h_in      = (const float*)d_in[0];
  const float* norm1_w   = (const float*)d_in[1];
  const float* in_proj_w = (const float*)d_in[2];
  const float* conv_w    = (const float*)d_in[3];
  const float* conv_b    = (const float*)d_in[4];
  const float* x_proj_w  = (const float*)d_in[5];
  const float* dt_proj_w = (const float*)d_in[6];
  const float* dt_proj_b = (const float*)d_in[7];
  const float* A_log     = (const float*)d_in[8];
  const float* D_param   = (const float*)d_in[9];
  const float* out_proj_w= (const float*)d_in[10];
  const float* norm2_w   = (const float*)d_in[11];
  const float* fc1_w     = (const float*)d_in[12];
  const float* fc1_b     = (const float*)d_in[13];
  const float* fc2_w     = (const float*)d_in[14];
  const float* fc2_b     = (const float*)d_in[15];
  float* out = (float*)d_out;

  char* ws = (char*)d_ws;
  __bf16* u_bf   = (__bf16*)(ws);                         // 0..4 MB
  __bf16* xz_bf  = (__bf16*)(ws + ((size_t) 4 << 20));    // 4..20 MB (bf16 2048x4096)
  __bf16* m1_bf  = (__bf16*)(ws + ((size_t) 4 << 20));    // reuses xz (dead by fc1)
  __bf16* xc     = (__bf16*)(ws + ((size_t)20 << 20));    // 20..28 MB
  float*  xdbl   = (float*) (ws + ((size_t)28 << 20));    // 28..29 MB (768 KB)
  __bf16* xdbl_bf= (__bf16*)(ws + ((size_t)29 << 20));    // 29..29.5 MB
  float*  dtb    = (float*) (ws + ((size_t)30 << 20));    // 30..46 MB
  float*  hch    = (float*) (ws + ((size_t)46 << 20));    // 46..62 MB
  float*  sdt    = (float*) (ws + ((size_t)62 << 20));    // 62..63 MB
  __bf16* y_bf   = (__bf16*)(ws + ((size_t)63 << 20));    // 63..71 MB
  __bf16* W1     = (__bf16*)(ws + ((size_t)71 << 20));    // 71..79 MB (in_proj -> fc1)
  __bf16* W2     = (__bf16*)(ws + ((size_t)79 << 20));    // 79..87 MB (out_proj -> fc2)
  __bf16* W3     = (__bf16*)(ws + ((size_t)87 << 20));    // x_proj (384 KB)
  __bf16* Wdt    = (__bf16*)(ws + ((size_t)88 << 20));    // dt_proj (256 KB)

  const int M = BB * LL;  // 2048

  // weight converts
  f2bf_k<<<(2 * DI * DD) / 1024, 256, 0, stream>>>(in_proj_w, W1, 2 * DI * DD);
  f2bf_k<<<(XD * DI) / 1024, 256, 0, stream>>>(x_proj_w, W3, XD * DI);
  f2bf_k<<<(DI * DTR) / 1024, 256, 0, stream>>>(dt_proj_w, Wdt, DI * DTR);

  // 1. u = rmsnorm(h, norm1_w) -> bf16
  rmsnorm_bf_k<<<M, 256, 0, stream>>>(h_in, norm1_w, u_bf);
  // 2. xz = u @ in_proj_w^T  (2048 x 4096 x 1024) -> bf16
  mfma_gemm<128, 4, true, 0, false, false, 1, false><<<dim3(4096 / 128, M / 128), 256, 0, stream>>>(
      u_bf, DD, W1, nullptr, nullptr, xz_bf, M, 2 * DI, DD);
  // 3. xc = silu(causal_conv(x)) -> bf16
  conv_silu_k<<<(BB * LL * (DI / 4)) / 256, 256, 0, stream>>>(xz_bf, conv_w, conv_b, xc);
  // 4. xdbl = xc @ x_proj_w^T  (2048 x 96 x 2048), split-K=8 atomic fp32
  hipMemsetAsync(xdbl, 0, (size_t)M * XD * 4, stream);
  mfma_gemm<32, 1, false, 0, false, false, 8, true><<<dim3(XD / 32, M / 128, 8), 256, 0, stream>>>(
      xc, DI, W3, nullptr, nullptr, xdbl, M, XD, DI);
  // 4b. xdbl -> bf16 (for dt_proj A operand)
  f2bf_k<<<(M * XD) / 1024, 256, 0, stream>>>(xdbl, xdbl_bf, M * XD);
  // 5. dt = softplus(xdbl[:, :64] @ dt_proj_w^T + b)  (2048 x 2048 x 64) MFMA
  mfma_gemm<128, 4, false, 2, true, false, 1, false><<<dim3(DI / 128, M / 128), 256, 0, stream>>>(
      xdbl_bf, XD, Wdt, dt_proj_b, nullptr, dtb, M, DI, DTR);
  // 6-8. chunked selective scan + fused gating -> y_bf
  scan1_k<<<BB * NC * (DI / 256), 256, 0, stream>>>(dtb, xc, xdbl, A_log, hch, sdt);
  scan2_k<<<BB * DS * (DI / 256), 256, 0, stream>>>(hch, sdt, A_log);
  scan3_k<<<BB * NC * (DI / 256), 256, 0, stream>>>(dtb, xc, xz_bf, xdbl, hch, A_log, D_param, y_bf);
  // 9. h2 = h + y @ out_proj_w^T  (2048 x 1024 x 2048), 128x128 split-K=4 -> d_out
  f2bf_k<<<(DD * DI) / 1024, 256, 0, stream>>>(out_proj_w, W2, DD * DI);
  hipMemsetAsync(out, 0, (size_t)M * DD * 4, stream);
  mfma_gemm<128, 4, false, 0, false, true, 4, true><<<dim3(DD / 128, M / 128, 4), 256, 0, stream>>>(
      y_bf, DI, W2, nullptr, h_in, out, M, DD, DI);
  // 10. hn = rmsnorm(h2, norm2_w) -> bf16
  rmsnorm_bf_k<<<M, 256, 0, stream>>>(out, norm2_w, u_bf);
  // 11. m1 = silu(hn @ fc1_w^T + fc1_b)  (2048 x 4096 x 1024) -> bf16
  f2bf_k<<<(4 * DD * DD) / 1024, 256, 0, stream>>>(fc1_w, W1, 4 * DD * DD);
  mfma_gemm<128, 4, true, 1, true, false, 1, false><<<dim3(4 * DD / 128, M / 128), 256, 0, stream>>>(
      u_bf, DD, W1, fc1_b, nullptr, m1_bf, M, 4 * DD, DD);
  // 12. out += m1 @ fc2_w^T + fc2_b  (2048 x 1024 x 4096), 128x128 split-K=4 (out holds h2)
  f2bf_k<<<(DD * 4 * DD) / 1024, 256, 0, stream>>>(fc2_w, W2, DD * 4 * DD);
  mfma_gemm<128, 4, false, 0, true, false, 4, true><<<dim3(DD / 128, M / 128, 4), 256, 0, stream>>>(
      m1_bf, 4 * DD, W2, fc2_b, nullptr, out, M, DD, 4 * DD);
}

// Round 5
// 432.377 us; speedup vs baseline: 1.1445x; 1.1445x over previous
//
#include <hip/hip_runtime.h>
#include <math.h>

#define BB 2
#define LL 1024
#define DD 1024
#define DI 2048
#define DS 16
#define DC 4
#define DTR 64
#define XD 96      // DTR + 2*DS
#define NC 64      // scan chunks
#define CLEN 16    // steps per chunk (NC*CLEN == LL)

typedef __bf16 bf16x8 __attribute__((ext_vector_type(8)));
typedef __bf16 bf16x4 __attribute__((ext_vector_type(4)));
typedef float  f32x4  __attribute__((ext_vector_type(4)));
typedef const __attribute__((address_space(1))) void* gas_ptr;
typedef __attribute__((address_space(3))) void*       las_ptr;

__device__ __forceinline__ float silu_f(float v){ return v / (1.f + expf(-v)); }

// ------------- fused fp32->bf16 weight converts (6 segments) ----------
struct F2BSegs {
  const float* src[6];
  __bf16* dst[6];
  int blk_end[6];   // exclusive prefix sums in blocks (1024 elements per block)
};
__global__ __launch_bounds__(256) void f2bf_multi_k(F2BSegs segs) {
  int b = blockIdx.x;
  int seg = 0, prev = 0;
  #pragma unroll
  for (int i = 0; i < 6; ++i) {
    if (b >= segs.blk_end[i]) { seg = i + 1; prev = segs.blk_end[i]; }
  }
  int i = ((b - prev) * 256 + threadIdx.x) * 4;
  float4 v = *(const float4*)(segs.src[seg] + i);
  __bf16* o = segs.dst[seg];
  o[i + 0] = (__bf16)v.x; o[i + 1] = (__bf16)v.y;
  o[i + 2] = (__bf16)v.z; o[i + 3] = (__bf16)v.w;
}

// ---------------- fp32 -> bf16 convert (n % 1024 == 0) ----------------
__global__ __launch_bounds__(256) void f2bf_k(const float* __restrict__ x,
                                              __bf16* __restrict__ o, int n) {
  int i = (blockIdx.x * 256 + threadIdx.x) * 4;
  float4 v = *(const float4*)(x + i);
  o[i + 0] = (__bf16)v.x; o[i + 1] = (__bf16)v.y;
  o[i + 2] = (__bf16)v.z; o[i + 3] = (__bf16)v.w;
}

// ---------------- rmsnorm: one block per row of D=1024, bf16 out ------
__global__ __launch_bounds__(256) void rmsnorm_bf_k(const float* __restrict__ x,
                                                    const float* __restrict__ w,
                                                    __bf16* __restrict__ o) {
  int row = blockIdx.x;
  const float* xr = x + (size_t)row * DD;
  int i4 = threadIdx.x * 4;
  float4 v = *(const float4*)(xr + i4);
  float ss = v.x * v.x + v.y * v.y + v.z * v.z + v.w * v.w;
  for (int off = 32; off; off >>= 1) ss += __shfl_down(ss, off, 64);
  __shared__ float red[4];
  int lane = threadIdx.x & 63, wv = threadIdx.x >> 6;
  if (!lane) red[wv] = ss;
  __syncthreads();
  if (!threadIdx.x) { float t = red[0] + red[1] + red[2] + red[3]; red[0] = rsqrtf(t / DD + 1e-6f); }
  __syncthreads();
  float rs = red[0];
  float4 wv4 = *(const float4*)(w + i4);
  __bf16* orow = o + (size_t)row * DD;
  orow[i4 + 0] = (__bf16)(wv4.x * v.x * rs);
  orow[i4 + 1] = (__bf16)(wv4.y * v.y * rs);
  orow[i4 + 2] = (__bf16)(wv4.z * v.z * rs);
  orow[i4 + 3] = (__bf16)(wv4.w * v.w * rs);
}

// ---------------- bf16 MFMA GEMM, BK=64: C[M,N] = ep(A @ W^T) ---------
// BM=128 fixed, BN = NI*32. 4 waves 2x2. XOR chunk swizzle vs bank conflicts.
// ACT: 0=none 1=silu 2=softplus. OUT_BF: store bf16 else fp32.
// SPLITK>1 requires ATOMIC; bias/resid applied by split kz==0 only.
template<int NI, bool OUT_BF, int ACT, bool BIAS, bool RESID, int SPLITK, bool ATOMIC>
__global__ __launch_bounds__(256) void mfma_gemm(const __bf16* __restrict__ A, int lda,
                                                 const __bf16* __restrict__ W,
                                                 const float* __restrict__ bias,
                                                 const float* __restrict__ resid,
                                                 void* __restrict__ Cout,
                                                 int M, int N, int K) {
  constexpr int BN = NI * 32;
  __shared__ __align__(16) __bf16 As[128 * 64];
  __shared__ __align__(16) __bf16 Bs[BN * 64];
  const int tid = threadIdx.x;
  const int m0 = blockIdx.y * 128;
  const int n0 = blockIdx.x * BN;
  const int kz = blockIdx.z;
  const int lane = tid & 63;
  const int wave = tid >> 6;
  const int wm = wave >> 1, wn = wave & 1;
  const int row16 = lane & 15, quad = lane >> 4;
  const int sw = row16 & 7;    // fragment-read swizzle key

  f32x4 acc[4][NI];
  #pragma unroll
  for (int i = 0; i < 4; ++i)
    #pragma unroll
    for (int j = 0; j < NI; ++j) acc[i][j] = (f32x4){0.f, 0.f, 0.f, 0.f};

  const int kspan = K / SPLITK;
  const int kbeg = kz * kspan;
  for (int k0 = kbeg; k0 < kbeg + kspan; k0 += 64) {
    // A tile: 128 rows x 64 k = 16 KB = 1024 chunks of 16B; 8 chunks/row.
    // physical slot (r,c) holds global chunk c^(r&7)  (bank-conflict swizzle)
    #pragma unroll
    for (int t = 0; t < 4; ++t) {
      int flat = t * 256 + tid;
      int r = flat >> 3, c = flat & 7;
      int cs = c ^ (r & 7);
      __builtin_amdgcn_global_load_lds(
          (gas_ptr)(A + (size_t)(m0 + r) * lda + k0 + cs * 8),
          (las_ptr)(As + flat * 8), 16, 0, 0);
    }
    // B tile: BN rows x 64 k; NI*256 chunks
    #pragma unroll
    for (int t = 0; t < NI; ++t) {
      int flat = t * 256 + tid;
      int r = flat >> 3, c = flat & 7;
      int cs = c ^ (r & 7);
      __builtin_amdgcn_global_load_lds(
          (gas_ptr)(W + (size_t)(n0 + r) * K + k0 + cs * 8),
          (las_ptr)(Bs + flat * 8), 16, 0, 0);
    }
    __syncthreads();
    bf16x8 af[4][2], bfr[NI][2];
    #pragma unroll
    for (int kk = 0; kk < 2; ++kk) {
      #pragma unroll
      for (int mi = 0; mi < 4; ++mi) {
        int r = wm * 64 + mi * 16 + row16;
        af[mi][kk] = *(const bf16x8*)&As[r * 64 + ((((kk << 2) | quad) ^ sw) << 3)];
      }
      #pragma unroll
      for (int ni = 0; ni < NI; ++ni) {
        int r = wn * NI * 16 + ni * 16 + row16;
        bfr[ni][kk] = *(const bf16x8*)&Bs[r * 64 + ((((kk << 2) | quad) ^ sw) << 3)];
      }
    }
    #pragma unroll
    for (int kk = 0; kk < 2; ++kk)
      #pragma unroll
      for (int mi = 0; mi < 4; ++mi)
        #pragma unroll
        for (int ni = 0; ni < NI; ++ni)
          acc[mi][ni] = __builtin_amdgcn_mfma_f32_16x16x32_bf16(af[mi][kk], bfr[ni][kk], acc[mi][ni], 0, 0, 0);
    __syncthreads();
  }

  // epilogue: D[row=quad*4+r][col=lane&15] per 16x16 frag
  #pragma unroll
  for (int mi = 0; mi < 4; ++mi) {
    #pragma unroll
    for (int ni = 0; ni < NI; ++ni) {
      #pragma unroll
      for (int r = 0; r < 4; ++r) {
        int gm = m0 + wm * 64 + mi * 16 + quad * 4 + r;
        int gn = n0 + wn * NI * 16 + ni * 16 + row16;
        float v = acc[mi][ni][r];
        if (ATOMIC) {
          if (kz == 0) {
            if (BIAS)  v += bias[gn];
            if (RESID) v += resid[(size_t)gm * N + gn];
          }
          atomicAdd(&((float*)Cout)[(size_t)gm * N + gn], v);
        } else {
          if (BIAS) v += bias[gn];
          if (ACT == 1) v = silu_f(v);
          else if (ACT == 2) v = (v > 20.f) ? v : log1pf(expf(v));
          if (RESID) v += resid[(size_t)gm * N + gn];
          if (OUT_BF) ((__bf16*)Cout)[(size_t)gm * N + gn] = (__bf16)v;
          else        ((float*)Cout)[(size_t)gm * N + gn] = v;
        }
      }
    }
  }
}

// ---------------- causal depthwise conv (DC=4) + silu, bf16 in/out ----
__global__ __launch_bounds__(256) void conv_silu_k(const __bf16* __restrict__ xz,
                                                   const float* __restrict__ cw,
                                                   const float* __restrict__ cb,
                                                   __bf16* __restrict__ xc) {
  size_t idx = (size_t)blockIdx.x * 256 + threadIdx.x;   // over BB*LL*(DI/4)
  int d4 = (int)(idx % (DI / 4)) * 4;
  size_t bl = idx / (DI / 4);
  int l = (int)(bl % LL);
  size_t rowbase = (bl - l) * (size_t)(2 * DI);
  float4 cbv = *(const float4*)(cb + d4);
  float a0 = cbv.x, a1 = cbv.y, a2 = cbv.z, a3 = cbv.w;
  #pragma unroll
  for (int k = 0; k < DC; ++k) {
    int ls = l + k - (DC - 1);
    if (ls >= 0) {
      bf16x4 xv = *(const bf16x4*)(xz + rowbase + (size_t)ls * (2 * DI) + d4);
      a0 += cw[(d4 + 0) * DC + k] * (float)xv[0];
      a1 += cw[(d4 + 1) * DC + k] * (float)xv[1];
      a2 += cw[(d4 + 2) * DC + k] * (float)xv[2];
      a3 += cw[(d4 + 3) * DC + k] * (float)xv[3];
    }
  }
  __bf16* o = xc + bl * DI + d4;
  o[0] = (__bf16)silu_f(a0); o[1] = (__bf16)silu_f(a1);
  o[2] = (__bf16)silu_f(a2); o[3] = (__bf16)silu_f(a3);
}

// ---------------- selective scan, 3-pass chunked (dt in bf16) ---------
__global__ __launch_bounds__(256) void scan1_k(const __bf16* __restrict__ dt,
                                               const __bf16* __restrict__ xc,
                                               const float* __restrict__ xdbl,
                                               const float* __restrict__ A_log,
                                               float* __restrict__ hch,
                                               float* __restrict__ sdt) {
  const int DBLK = DI / 256;
  int dblk = blockIdx.x % DBLK;
  int c = (blockIdx.x / DBLK) % NC;
  int b = blockIdx.x / (DBLK * NC);
  int d = dblk * 256 + threadIdx.x;
  __shared__ float Bs[CLEN][DS];
  if (threadIdx.x < CLEN * DS) {
    int ll = threadIdx.x / DS, s = threadIdx.x % DS;
    Bs[ll][s] = xdbl[((size_t)b * LL + c * CLEN + ll) * XD + DTR + s];
  }
  __syncthreads();
  float As[DS];
  #pragma unroll
  for (int s = 0; s < DS; ++s) As[s] = -expf(A_log[(size_t)d * DS + s]);
  float h[DS] = {};
  float sum_dt = 0.f;
  for (int t = 0; t < CLEN; ++t) {
    size_t bl = (size_t)b * LL + c * CLEN + t;
    float dtv = (float)dt[bl * DI + d];
    float xv = (float)xc[bl * DI + d];
    float cc = dtv * xv;
    sum_dt += dtv;
    #pragma unroll
    for (int s = 0; s < DS; ++s) h[s] = expf(dtv * As[s]) * h[s] + cc * Bs[t][s];
  }
  size_t base = (((size_t)b * NC + c) * DS) * DI + d;
  #pragma unroll
  for (int s = 0; s < DS; ++s) hch[base + (size_t)s * DI] = h[s];
  sdt[((size_t)b * NC + c) * DI + d] = sum_dt;
}

__global__ __launch_bounds__(256) void scan2_k(float* __restrict__ hch,
                                               const float* __restrict__ sdt,
                                               const float* __restrict__ A_log) {
  const int DBLK = DI / 256;
  int dblk = blockIdx.x % DBLK;
  int s = (blockIdx.x / DBLK) % DS;
  int b = blockIdx.x / (DBLK * DS);
  int d = dblk * 256 + threadIdx.x;
  float As = -expf(A_log[(size_t)d * DS + s]);
  float hs = 0.f;
  for (int c = 0; c < NC; ++c) {
    size_t idx = (((size_t)b * NC + c) * DS + s) * DI + d;
    float local_final = hch[idx];
    hch[idx] = hs;
    float sum_dt = sdt[((size_t)b * NC + c) * DI + d];
    hs = expf(sum_dt * As) * hs + local_final;
  }
}

__global__ __launch_bounds__(256) void scan3_k(const __bf16* __restrict__ dt,
                                               const __bf16* __restrict__ xc,
                                               const __bf16* __restrict__ xz,
                                               const float* __restrict__ xdbl,
                                               const float* __restrict__ hch,
                                               const float* __restrict__ A_log,
                                               const float* __restrict__ Dp,
                                               __bf16* __restrict__ yb) {
  const int DBLK = DI / 256;
  int dblk = blockIdx.x % DBLK;
  int c = (blockIdx.x / DBLK) % NC;
  int b = blockIdx.x / (DBLK * NC);
  int d = dblk * 256 + threadIdx.x;
  __shared__ float Bs[CLEN][DS], Cs[CLEN][DS];
  if (threadIdx.x < CLEN * DS) {
    int ll = threadIdx.x / DS, s = threadIdx.x % DS;
    size_t bl = (size_t)b * LL + c * CLEN + ll;
    Bs[ll][s] = xdbl[bl * XD + DTR + s];
    Cs[ll][s] = xdbl[bl * XD + DTR + DS + s];
  }
  __syncthreads();
  float As[DS], h[DS];
  #pragma unroll
  for (int s = 0; s < DS; ++s) As[s] = -expf(A_log[(size_t)d * DS + s]);
  size_t base = (((size_t)b * NC + c) * DS) * DI + d;
  #pragma unroll
  for (int s = 0; s < DS; ++s) h[s] = hch[base + (size_t)s * DI];
  float Dv = Dp[d];
  for (int t = 0; t < CLEN; ++t) {
    size_t bl = (size_t)b * LL + c * CLEN + t;
    float dtv = (float)dt[bl * DI + d];
    float xv = (float)xc[bl * DI + d];
    float cc = dtv * xv;
    float y = 0.f;
    #pragma unroll
    for (int s = 0; s < DS; ++s) {
      h[s] = expf(dtv * As[s]) * h[s] + cc * Bs[t][s];
      y += h[s] * Cs[t][s];
    }
    float zv = (float)xz[bl * (size_t)(2 * DI) + DI + d];
    yb[bl * DI + d] = (__bf16)((y + Dv * xv) * silu_f(zv));
  }
}

// ---------------- launch ----------------
extern "C" void kernel_launch(void* const* d_in, const int* in_sizes, int n_in,
                              void* d_out, int out_size, void* d_ws, size_t ws_size,
                              hipStream_t stream) {
  const float* h_in      = (const float*)d_in[0];
  const float* norm1_w   = (const float*)d_in[1];
  const float* in_proj_w = (const float*)d_in[2];
  const float* conv_w    = (const float*)d_in[3];
  const float* conv_b    = (const float*)d_in[4];
  const float* x_proj_w  = (const float*)d_in[5];
  const float* dt_proj_w = (const float*)d_in[6];
  const float* dt_proj_b = (const float*)d_in[7];
  const float* A_log     = (const float*)d_in[8];
  const float* D_param   = (const float*)d_in[9];
  const float* out_proj_w= (const float*)d_in[10];
  const float* norm2_w   = (const float*)d_in[11];
  const float* fc1_w     = (const float*)d_in[12];
  const float* fc1_b     = (const float*)d_in[13];
  const float* fc2_w     = (const float*)d_in[14];
  const float* fc2_b     = (const float*)d_in[15];
  float* out = (float*)d_out;

  char* ws = (char*)d_ws;
  __bf16* u_bf   = (__bf16*)(ws);                         // 0..4 MB
  __bf16* xz_bf  = (__bf16*)(ws + ((size_t) 4 << 20));    // 4..20 MB
  __bf16* m1_bf  = (__bf16*)(ws + ((size_t) 4 << 20));    // reuses xz (dead by fc1)
  __bf16* xc     = (__bf16*)(ws + ((size_t)20 << 20));    // 20..28 MB
  float*  xdbl   = (float*) (ws + ((size_t)28 << 20));    // 768 KB
  __bf16* xdbl_bf= (__bf16*)(ws + ((size_t)29 << 20));    // 384 KB
  __bf16* dtb_bf = (__bf16*)(ws + ((size_t)30 << 20));    // 30..38 MB
  float*  hch    = (float*) (ws + ((size_t)38 << 20));    // 38..54 MB
  float*  sdt    = (float*) (ws + ((size_t)54 << 20));    // 1 MB
  __bf16* y_bf   = (__bf16*)(ws + ((size_t)55 << 20));    // 55..63 MB
  __bf16* Wip    = (__bf16*)(ws + ((size_t)63 << 20));    // 63..71 MB in_proj
  __bf16* Wxp    = (__bf16*)(ws + ((size_t)71 << 20));    // 384 KB x_proj
  __bf16* Wdt    = (__bf16*)(ws + ((size_t)72 << 20));    // 256 KB dt_proj
  __bf16* Wop    = (__bf16*)(ws + ((size_t)73 << 20));    // 73..77 MB out_proj
  __bf16* Wf1    = (__bf16*)(ws + ((size_t)77 << 20));    // 77..85 MB fc1
  __bf16* Wf2    = (__bf16*)(ws + ((size_t)85 << 20));    // 85..93 MB fc2

  const int M = BB * LL;  // 2048

  // one fused kernel for all 6 weight converts
  F2BSegs segs;
  segs.src[0] = in_proj_w;  segs.dst[0] = Wip;  int b0 = (2 * DI * DD) / 1024;
  segs.src[1] = x_proj_w;   segs.dst[1] = Wxp;  int b1 = (XD * DI) / 1024;
  segs.src[2] = dt_proj_w;  segs.dst[2] = Wdt;  int b2 = (DI * DTR) / 1024;
  segs.src[3] = out_proj_w; segs.dst[3] = Wop;  int b3 = (DD * DI) / 1024;
  segs.src[4] = fc1_w;      segs.dst[4] = Wf1;  int b4 = (4 * DD * DD) / 1024;
  segs.src[5] = fc2_w;      segs.dst[5] = Wf2;  int b5 = (DD * 4 * DD) / 1024;
  segs.blk_end[0] = b0;
  segs.blk_end[1] = b0 + b1;
  segs.blk_end[2] = b0 + b1 + b2;
  segs.blk_end[3] = b0 + b1 + b2 + b3;
  segs.blk_end[4] = b0 + b1 + b2 + b3 + b4;
  segs.blk_end[5] = b0 + b1 + b2 + b3 + b4 + b5;
  f2bf_multi_k<<<segs.blk_end[5], 256, 0, stream>>>(segs);

  // 1. u = rmsnorm(h, norm1_w) -> bf16
  rmsnorm_bf_k<<<M, 256, 0, stream>>>(h_in, norm1_w, u_bf);
  // 2. xz = u @ in_proj_w^T  (2048 x 4096 x 1024), 128x64 tiles, 1024 blocks
  mfma_gemm<2, true, 0, false, false, 1, false><<<dim3(4096 / 64, M / 128), 256, 0, stream>>>(
      u_bf, DD, Wip, nullptr, nullptr, xz_bf, M, 2 * DI, DD);
  // 3. xc = silu(causal_conv(x)) -> bf16
  conv_silu_k<<<(BB * LL * (DI / 4)) / 256, 256, 0, stream>>>(xz_bf, conv_w, conv_b, xc);
  // 4. xdbl = xc @ x_proj_w^T  (2048 x 96 x 2048), split-K=16 atomic fp32
  hipMemsetAsync(xdbl, 0, (size_t)M * XD * 4, stream);
  mfma_gemm<1, false, 0, false, false, 16, true><<<dim3(XD / 32, M / 128, 16), 256, 0, stream>>>(
      xc, DI, Wxp, nullptr, nullptr, xdbl, M, XD, DI);
  // 4b. xdbl -> bf16 (dt_proj A operand)
  f2bf_k<<<(M * XD) / 1024, 256, 0, stream>>>(xdbl, xdbl_bf, M * XD);
  // 5. dt = softplus(xdbl[:, :64] @ dt_proj_w^T + b), single BK=64 step -> bf16
  mfma_gemm<2, true, 2, true, false, 1, false><<<dim3(DI / 64, M / 128), 256, 0, stream>>>(
      xdbl_bf, XD, Wdt, dt_proj_b, nullptr, dtb_bf, M, DI, DTR);
  // 6-8. chunked selective scan + fused gating -> y_bf
  scan1_k<<<BB * NC * (DI / 256), 256, 0, stream>>>(dtb_bf, xc, xdbl, A_log, hch, sdt);
  scan2_k<<<BB * DS * (DI / 256), 256, 0, stream>>>(hch, sdt, A_log);
  scan3_k<<<BB * NC * (DI / 256), 256, 0, stream>>>(dtb_bf, xc, xz_bf, xdbl, hch, A_log, D_param, y_bf);
  // 9. h2 = h + y @ out_proj_w^T  (2048 x 1024 x 2048), split-K=4, 1024 blocks
  hipMemsetAsync(out, 0, (size_t)M * DD * 4, stream);
  mfma_gemm<2, false, 0, false, true, 4, true><<<dim3(DD / 64, M / 128, 4), 256, 0, stream>>>(
      y_bf, DI, Wop, nullptr, h_in, out, M, DD, DI);
  // 10. hn = rmsnorm(h2, norm2_w) -> bf16
  rmsnorm_bf_k<<<M, 256, 0, stream>>>(out, norm2_w, u_bf);
  // 11. m1 = silu(hn @ fc1_w^T + fc1_b)  (2048 x 4096 x 1024), 1024 blocks
  mfma_gemm<2, true, 1, true, false, 1, false><<<dim3(4 * DD / 64, M / 128), 256, 0, stream>>>(
      u_bf, DD, Wf1, fc1_b, nullptr, m1_bf, M, 4 * DD, DD);
  // 12. out += m1 @ fc2_w^T + fc2_b  (2048 x 1024 x 4096), split-K=4, 1024 blocks
  mfma_gemm<2, false, 0, true, false, 4, true><<<dim3(DD / 64, M / 128, 4), 256, 0, stream>>>(
      m1_bf, 4 * DD, Wf2, fc2_b, nullptr, out, M, DD, 4 * DD);
}